// Round 12
// baseline (269.406 us; speedup 1.0000x reference)
//
#include <hip/hip_runtime.h>

typedef unsigned short u16;
typedef unsigned int u32;
typedef __bf16 bf16x8 __attribute__((ext_vector_type(8)));
typedef float f32x4 __attribute__((ext_vector_type(4)));
typedef u16 u16x4 __attribute__((ext_vector_type(4)));
typedef u16 u16x8 __attribute__((ext_vector_type(8)));

#define T_SEQ 2048
#define DMODEL 2048
#define NQKV 6144
#define HD 128
#define NH 16
#define MROWS 4096

__device__ __forceinline__ u16 f2b(float f) {
  union { float f; u32 u; } a; a.f = f;
  u32 r = a.u + 0x7fffu + ((a.u >> 16) & 1u);
  return (u16)(r >> 16);
}
__device__ __forceinline__ float b2f(u16 h) {
  union { u32 u; float f; } a; a.u = ((u32)h) << 16;
  return a.f;
}
__device__ __forceinline__ void g2l16(const u16* g, u16* l) {
  __builtin_amdgcn_global_load_lds((const __attribute__((address_space(1))) u32*)g,
                                   (__attribute__((address_space(3))) u32*)l, 16, 0, 0);
}

__global__ void k_f32_to_bf16(const float* __restrict__ in, u16* __restrict__ out, int n) {
  int i = (blockIdx.x * 256 + threadIdx.x) * 8;
  if (i >= n) return;
  float4 a = *(const float4*)(in + i);
  float4 b = *(const float4*)(in + i + 4);
  u16x8 v;
  v[0] = f2b(a.x); v[1] = f2b(a.y); v[2] = f2b(a.z); v[3] = f2b(a.w);
  v[4] = f2b(b.x); v[5] = f2b(b.y); v[6] = f2b(b.z); v[7] = f2b(b.w);
  *(u16x8*)(out + i) = v;
}

// out[c][r] = bf16(in[r][c]); in is R x C f32
__global__ void k_transpose_bf16(const float* __restrict__ in, u16* __restrict__ out,
                                 int R, int C) {
  __shared__ u16 tile[32][33];
  const int c0 = blockIdx.x * 32, r0 = blockIdx.y * 32;
  const int tx = threadIdx.x & 31, ty = threadIdx.x >> 5;
#pragma unroll
  for (int i = 0; i < 32; i += 8)
    tile[ty + i][tx] = f2b(in[(size_t)(r0 + ty + i) * C + c0 + tx]);
  __syncthreads();
#pragma unroll
  for (int i = 0; i < 32; i += 8)
    out[(size_t)(c0 + ty + i) * R + r0 + tx] = tile[tx][ty + i];
}

// ---------------------------------------------------------------------------
// QKV GEMM with fused RoPE + head-scatter epilogue (m97 128x128 structure).
// LESSONS: no occupancy attributes (r9); acc[][] only compile-time-indexed
// (r10, rule #20). NEW (r12): LDS-BOUNCE epilogue — acc is dumped to LDS
// (fully unrolled writes), then a bounded-unroll loop (LDS-indexed: legal)
// reads back + RoPE/packs + stores. This kills the ~50-temp batched-store
// peak that pinned VGPR at 120 and occupancy at 20%.
// q/k stored with interleaved d-permutation (d<64->2d, d>=64->2(d-64)+1);
// QK^T invariant since Q,K share it. V transposed to vtb[bh][d][t].
// ---------------------------------------------------------------------------
__global__ __launch_bounds__(256) void k_gemm_qkv(const u16* __restrict__ A,
                                                  const u16* __restrict__ B,
                                                  u16* __restrict__ qr,
                                                  u16* __restrict__ kr,
                                                  u16* __restrict__ vtb) {
  __shared__ __align__(16) u16 lsmem[2][128 * 64];
  u16* lA = lsmem[0];
  u16* lB = lsmem[1];
  float* ldsF = (float*)lsmem;               // 8192 f32 = 64 rows x 128 cols
  const int K = DMODEL;
  const int tid = threadIdx.x;
  const int wid = tid >> 6, lane = tid & 63;
  const int g = lane >> 4, q = lane & 15;
  const int wr = wid >> 1, wc = wid & 1;
  const int bn = blockIdx.x, bm = blockIdx.y;
  const int l8 = lane >> 3, l7 = lane & 7;
  const f32x4 fzero = {0.f, 0.f, 0.f, 0.f};
  f32x4 acc[4][4];
#pragma unroll
  for (int m = 0; m < 4; ++m)
#pragma unroll
    for (int n = 0; n < 4; ++n) acc[m][n] = fzero;

  const u16* Ab = A + (size_t)bm * 128 * K;
  const u16* Bb = B + (size_t)bn * 128 * K;

  for (int k0 = 0; k0 < K; k0 += 64) {
    __syncthreads();
#pragma unroll
    for (int i = 0; i < 4; ++i) {
      int chunk = wid * 4 + i;
      int row = chunk * 8 + l8;
      int scol = (l7 * 8) ^ ((row & 7) << 3);
      g2l16(Ab + (size_t)row * K + k0 + scol, lA + chunk * 512);
      g2l16(Bb + (size_t)row * K + k0 + scol, lB + chunk * 512);
    }
    __syncthreads();
#pragma unroll
    for (int kk = 0; kk < 2; ++kk) {
      bf16x8 af[4], bfr[4];
#pragma unroll
      for (int m = 0; m < 4; ++m) {
        int row = wr * 64 + m * 16 + q;
        int col = (kk * 32 + g * 8) ^ ((row & 7) << 3);
        af[m] = *(const bf16x8*)(lA + row * 64 + col);
      }
#pragma unroll
      for (int n = 0; n < 4; ++n) {
        int row = wc * 32 + (n & 1) * 16 + (n >> 1) * 64 + q;  // paired-col mapping
        int col = (kk * 32 + g * 8) ^ ((row & 7) << 3);
        bfr[n] = *(const bf16x8*)(lB + row * 64 + col);
      }
#pragma unroll
      for (int m = 0; m < 4; ++m)
#pragma unroll
        for (int n = 0; n < 4; ++n)
          acc[m][n] = __builtin_amdgcn_mfma_f32_16x16x32_bf16(af[m], bfr[n], acc[m][n], 0, 0, 0);
    }
  }
  __builtin_amdgcn_sched_barrier(0);

  // ---- LDS-bounce fused epilogue ----
  const int h = bn & 15;
  const int which = bn >> 4;                 // 0=q, 1=k, 2=v
  const int b = bm >> 4;
  const int bh = b * 16 + h;
  const int tbase = (bm & 15) * 128;
  const float sc = (which == 0) ? 0.08838834764831845f : 1.0f;
  u16* dst = (which ? kr : qr) + (size_t)bh * T_SEQ * HD;
  u16* vdst = vtb + (size_t)bh * HD * T_SEQ;
  // inv_freq for the q/k reader: dm = lane (0..63), hoisted out of passes
  const float inv = exp2f(-(float)lane * 0.20762050592046521f);

#pragma unroll
  for (int p = 0; p < 2; ++p) {
    __syncthreads();
    // Write acc[2p], acc[2p+1] -> ldsF as f32. Fully unrolled (acc indexing
    // compile-time). Logical row lr = wr*32 + mm*16 + g*4 + r in [0,64);
    // col c in [0,128); XOR-swizzle ((lr&7)<<2) keeps conflicts at 2-way.
#pragma unroll
    for (int mm = 0; mm < 2; ++mm) {
#pragma unroll
      for (int n = 0; n < 4; ++n) {
        int c = wc * 32 + (n & 1) * 16 + (n >> 1) * 64 + q;
#pragma unroll
        for (int r = 0; r < 4; ++r) {
          int lr = wr * 32 + mm * 16 + g * 4 + r;
          ldsF[lr * 128 + (c ^ ((lr & 7) << 2))] = acc[2 * p + mm][n][r];
        }
      }
    }
    __syncthreads();
    if (which == 2) {
      // V reader: item = j*256+tid -> d = item>>4, t-quad tq = item&15.
#pragma unroll 2
      for (int j = 0; j < 8; ++j) {
        int d = j * 16 + (tid >> 4);
        int tq = tid & 15;
        int lr0 = tq * 4;
        u16x4 pk;
#pragma unroll
        for (int rr = 0; rr < 4; ++rr) {
          int lr = lr0 + rr;
          pk[rr] = f2b(ldsF[lr * 128 + (d ^ ((lr & 7) << 2))]);
        }
        int t0 = tbase + (lr0 >> 5) * 64 + p * 32 + (lr0 & 31);
        *(u16x4*)(vdst + (size_t)d * T_SEQ + t0) = pk;
      }
    } else {
      // q/k RoPE reader: row = wid*16+j, dm = lane; one u32 store per item.
#pragma unroll 2
      for (int j = 0; j < 16; ++j) {
        int row = wid * 16 + j;
        int xk = (row & 7) << 2;
        float x0 = ldsF[row * 128 + (lane ^ xk)];
        float x1 = ldsF[row * 128 + ((lane + 64) ^ xk)];
        int t = tbase + (row >> 5) * 64 + p * 32 + (row & 31);
        float s, c;
        __sincosf((float)t * inv, &s, &c);
        u32 pk = (u32)f2b((x0 * c - x1 * s) * sc) |
                 ((u32)f2b((x1 * c + x0 * s) * sc) << 16);
        *(u32*)(dst + (size_t)t * HD + lane * 2) = pk;  // interleaved d
      }
    }
  }
}

// m97-style 128x128 GEMM for the output projection (EPI=1: f32 out).
template <int EPI>
__global__ __launch_bounds__(256) void k_gemm_nt(const u16* __restrict__ A,
                                                 const u16* __restrict__ B,
                                                 void* __restrict__ Cv,
                                                 int M, int N, int K) {
  __shared__ __align__(16) u16 lA[128 * 64];
  __shared__ __align__(16) u16 lB[128 * 64];
  const int tid = threadIdx.x;
  const int wid = tid >> 6, lane = tid & 63;
  const int g = lane >> 4, q = lane & 15;
  const int wr = wid >> 1, wc = wid & 1;
  const int bn = blockIdx.x, bm = blockIdx.y;
  const int l8 = lane >> 3, l7 = lane & 7;
  const f32x4 fzero = {0.f, 0.f, 0.f, 0.f};
  f32x4 acc[4][4];
#pragma unroll
  for (int m = 0; m < 4; ++m)
#pragma unroll
    for (int n = 0; n < 4; ++n) acc[m][n] = fzero;

  const u16* Ab = A + (size_t)bm * 128 * K;
  const u16* Bb = B + (size_t)bn * 128 * K;

  for (int k0 = 0; k0 < K; k0 += 64) {
    __syncthreads();
#pragma unroll
    for (int i = 0; i < 4; ++i) {
      int chunk = wid * 4 + i;
      int row = chunk * 8 + l8;
      int scol = (l7 * 8) ^ ((row & 7) << 3);
      g2l16(Ab + (size_t)row * K + k0 + scol, lA + chunk * 512);
      g2l16(Bb + (size_t)row * K + k0 + scol, lB + chunk * 512);
    }
    __syncthreads();
#pragma unroll
    for (int kk = 0; kk < 2; ++kk) {
      bf16x8 af[4], bfr[4];
#pragma unroll
      for (int m = 0; m < 4; ++m) {
        int row = wr * 64 + m * 16 + q;
        int col = (kk * 32 + g * 8) ^ ((row & 7) << 3);
        af[m] = *(const bf16x8*)(lA + row * 64 + col);
      }
#pragma unroll
      for (int n = 0; n < 4; ++n) {
        int row = wc * 64 + n * 16 + q;
        int col = (kk * 32 + g * 8) ^ ((row & 7) << 3);
        bfr[n] = *(const bf16x8*)(lB + row * 64 + col);
      }
#pragma unroll
      for (int m = 0; m < 4; ++m)
#pragma unroll
        for (int n = 0; n < 4; ++n)
          acc[m][n] = __builtin_amdgcn_mfma_f32_16x16x32_bf16(af[m], bfr[n], acc[m][n], 0, 0, 0);
    }
  }
  const int rbase = bm * 128 + wr * 64;
  const int cbase = bn * 128 + wc * 64;
#pragma unroll
  for (int m = 0; m < 4; ++m)
#pragma unroll
    for (int n = 0; n < 4; ++n) {
      int col = cbase + n * 16 + q;
#pragma unroll
      for (int r = 0; r < 4; ++r) {
        int row = rbase + m * 16 + g * 4 + r;
        if (EPI == 0)
          ((u16*)Cv)[(size_t)row * N + col] = f2b(acc[m][n][r]);
        else
          ((float*)Cv)[(size_t)row * N + col] = acc[m][n][r];
      }
    }
}

// Flash attention, triangle-folded at QBLK=64, grid (32 bh, 16): block does
// q-tile pair (31-y, y) = 33 k-tiles uniformly. Double-buffered K/V staging.
// Causal mask only on the diagonal tile. NEW (r12): defer-max (T13, THR=0) —
// skip o_acc rescale + corr shuffles when no lane's max grew.
__global__ __launch_bounds__(256) void k_attn(const u16* __restrict__ qr,
                                              const u16* __restrict__ kr,
                                              const u16* __restrict__ vtb,
                                              u16* __restrict__ ao) {
  __shared__ __align__(16) u16 lK[2][64 * 128];
  __shared__ __align__(16) u16 lV[2][128 * 64];
  __shared__ __align__(16) u16 lP[4][16 * 72];
  const int bh = blockIdx.x, b = bh >> 4, h = bh & 15;
  const int tid = threadIdx.x;
  const int wid = tid >> 6, lane = tid & 63;
  const int g = lane >> 4, q = lane & 15;
  const int l8 = lane >> 3, l7 = lane & 7;
  const u16* qb = qr + (size_t)bh * T_SEQ * HD;
  const u16* kbp = kr + (size_t)bh * T_SEQ * HD;
  const u16* vb = vtb + (size_t)bh * HD * T_SEQ;
  const f32x4 fzero = {0.f, 0.f, 0.f, 0.f};

  auto stageKV = [&](int kb, int bufI) {
#pragma unroll
    for (int i = 0; i < 4; ++i) {
      int chunk = wid * 4 + i;
      int row = chunk * 4 + g;
      int scol = (q * 8) ^ ((row & 7) << 3);
      g2l16(kbp + (size_t)(kb + row) * HD + scol, &lK[bufI][chunk * 512]);
    }
#pragma unroll
    for (int i = 0; i < 4; ++i) {
      int chunk = wid * 4 + i;
      int row = chunk * 8 + l8;
      int scol = (l7 * 8) ^ ((row & 7) << 3);
      g2l16(vb + (size_t)row * T_SEQ + kb + scol, &lV[bufI][chunk * 512]);
    }
  };

  for (int half = 0; half < 2; ++half) {
    const int qt = half ? (int)blockIdx.y : 31 - (int)blockIdx.y;
    const int qw0 = qt * 64 + wid * 16;

    bf16x8 qf[4];
#pragma unroll
    for (int ks = 0; ks < 4; ++ks)
      qf[ks] = *(const bf16x8*)(qb + (size_t)(qw0 + q) * HD + ks * 32 + g * 8);

    f32x4 o_acc[8];
#pragma unroll
    for (int n = 0; n < 8; ++n) o_acc[n] = fzero;
    float m_run = -1e30f, l_run = 0.f;

    const int ntiles = qt + 1;
    stageKV(0, 0);
    __syncthreads();                 // drains vmcnt -> buf0 ready
    for (int kt = 0; kt < ntiles; ++kt) {
      const int kb = kt * 64;
      const int cb = kt & 1;
      if (kt + 1 < ntiles) stageKV(kb + 64, cb ^ 1);   // prefetch next tile
      const u16* lKc = lK[cb];
      const u16* lVc = lV[cb];
      {
        f32x4 st[4];
#pragma unroll
        for (int m = 0; m < 4; ++m) st[m] = fzero;
#pragma unroll
        for (int ks = 0; ks < 4; ++ks) {
#pragma unroll
          for (int m = 0; m < 4; ++m) {
            int row = m * 16 + q;
            int col = (ks * 32 + g * 8) ^ ((row & 7) << 3);
            bf16x8 kf = *(const bf16x8*)(lKc + row * 128 + col);
            st[m] = __builtin_amdgcn_mfma_f32_16x16x32_bf16(kf, qf[ks], st[m], 0, 0, 0);
          }
        }
        const int qrow = qw0 + q;
        float p[4][4];
        float pmax = -1e30f;
        if (kt == ntiles - 1) {
          // diagonal tile: causal mask
#pragma unroll
          for (int m = 0; m < 4; ++m)
#pragma unroll
            for (int r = 0; r < 4; ++r) {
              int kcol = kb + m * 16 + g * 4 + r;
              float s = (kcol <= qrow) ? st[m][r] : -1e30f;
              p[m][r] = s;
              pmax = fmaxf(pmax, s);
            }
        } else {
#pragma unroll
          for (int m = 0; m < 4; ++m)
#pragma unroll
            for (int r = 0; r < 4; ++r) {
              p[m][r] = st[m][r];
              pmax = fmaxf(pmax, st[m][r]);
            }
        }
        pmax = fmaxf(pmax, __shfl_xor(pmax, 16));
        pmax = fmaxf(pmax, __shfl_xor(pmax, 32));
        // defer-max (T13, THR=0): skip rescale when no lane's max grew.
        const bool noresc = __all(pmax <= m_run);
        const float m_new = noresc ? m_run : fmaxf(m_run, pmax);
        float ls = 0.f;
#pragma unroll
        for (int m = 0; m < 4; ++m)
#pragma unroll
          for (int r = 0; r < 4; ++r) {
            float e = __expf(p[m][r] - m_new);
            p[m][r] = e;
            ls += e;
          }
        ls += __shfl_xor(ls, 16);
        ls += __shfl_xor(ls, 32);
#pragma unroll
        for (int m = 0; m < 4; ++m) {
#pragma unroll
          for (int rp = 0; rp < 2; ++rp) {
            u32 pk = (u32)f2b(p[m][rp * 2]) | ((u32)f2b(p[m][rp * 2 + 1]) << 16);
            *(u32*)(&lP[wid][q * 72 + m * 16 + g * 4 + rp * 2]) = pk;
          }
        }
        asm volatile("s_waitcnt lgkmcnt(0)" ::: "memory");
        __builtin_amdgcn_sched_barrier(0);
        if (noresc) {
          l_run += ls;
        } else {
          float corr = __expf(m_run - m_new);
          l_run = l_run * corr + ls;
          m_run = m_new;
          float corr4[4];
#pragma unroll
          for (int r = 0; r < 4; ++r) corr4[r] = __shfl(corr, g * 4 + r);
#pragma unroll
          for (int n = 0; n < 8; ++n) {
#pragma unroll
            for (int r = 0; r < 4; ++r) o_acc[n][r] *= corr4[r];
          }
        }
#pragma unroll
        for (int ks = 0; ks < 2; ++ks) {
          bf16x8 pf = *(const bf16x8*)(&lP[wid][q * 72 + ks * 32 + g * 8]);
#pragma unroll
          for (int n = 0; n < 8; ++n) {
            int row = n * 16 + q;
            int col = (ks * 32 + g * 8) ^ ((row & 7) << 3);
            bf16x8 vf = *(const bf16x8*)(lVc + row * 64 + col);
            o_acc[n] = __builtin_amdgcn_mfma_f32_16x16x32_bf16(pf, vf, o_acc[n], 0, 0, 0);
          }
        }
      }
      __syncthreads();               // drains vmcnt: prefetched buf ready; LDS reads done
    }
    float linv[4];
#pragma unroll
    for (int r = 0; r < 4; ++r) {
      float lv = __shfl(l_run, g * 4 + r);
      linv[r] = 1.0f / lv;
    }
#pragma unroll
    for (int n = 0; n < 8; ++n)
#pragma unroll
      for (int r = 0; r < 4; ++r) {
        int trow = qw0 + g * 4 + r;
        ao[(size_t)(b * T_SEQ + trow) * DMODEL + h * HD + n * 16 + q] = f2b(o_acc[n][r] * linv[r]);
      }
  }
}

extern "C" void kernel_launch(void* const* d_in, const int* in_sizes, int n_in,
                              void* d_out, int out_size, void* d_ws, size_t ws_size,
                              hipStream_t stream) {
  const float* x = (const float*)d_in[0];
  const float* w_qkv = (const float*)d_in[1];
  const float* w_out = (const float*)d_in[2];
  char* ws = (char*)d_ws;
  size_t off = 0;
  u16* xb = (u16*)(ws + off);    off += (size_t)MROWS * DMODEL * 2;   // also reused as ao
  u16* wqkvT = (u16*)(ws + off); off += (size_t)NQKV * DMODEL * 2;
  u16* woutT = (u16*)(ws + off); off += (size_t)DMODEL * DMODEL * 2;
  u16* qr = (u16*)(ws + off);    off += (size_t)32 * T_SEQ * HD * 2;
  u16* kr = (u16*)(ws + off);    off += (size_t)32 * T_SEQ * HD * 2;
  u16* vtb = (u16*)(ws + off);   off += (size_t)32 * T_SEQ * HD * 2;
  u16* ao = xb;

  k_f32_to_bf16<<<dim3(MROWS * DMODEL / (256 * 8)), 256, 0, stream>>>(x, xb, MROWS * DMODEL);
  k_transpose_bf16<<<dim3(NQKV / 32, DMODEL / 32), 256, 0, stream>>>(w_qkv, wqkvT, DMODEL, NQKV);
  k_transpose_bf16<<<dim3(DMODEL / 32, DMODEL / 32), 256, 0, stream>>>(w_out, woutT, DMODEL, DMODEL);
  k_gemm_qkv<<<dim3(48, 32), 256, 0, stream>>>(xb, wqkvT, qr, kr, vtb);
  k_attn<<<dim3(32, 16), 256, 0, stream>>>(qr, kr, vtb, ao);
  k_gemm_nt<1><<<dim3(DMODEL / 128, MROWS / 128), 256, 0, stream>>>(ao, woutT, d_out, MROWS, DMODEL, DMODEL);
}

// Round 13
// 266.953 us; speedup vs baseline: 1.0092x; 1.0092x over previous
//
#include <hip/hip_runtime.h>

typedef unsigned short u16;
typedef unsigned int u32;
typedef __bf16 bf16x8 __attribute__((ext_vector_type(8)));
typedef float f32x4 __attribute__((ext_vector_type(4)));
typedef u16 u16x4 __attribute__((ext_vector_type(4)));
typedef u16 u16x8 __attribute__((ext_vector_type(8)));

#define T_SEQ 2048
#define DMODEL 2048
#define NQKV 6144
#define HD 128
#define NH 16
#define MROWS 4096

__device__ __forceinline__ u16 f2b(float f) {
  union { float f; u32 u; } a; a.f = f;
  u32 r = a.u + 0x7fffu + ((a.u >> 16) & 1u);
  return (u16)(r >> 16);
}
__device__ __forceinline__ float b2f(u16 h) {
  union { u32 u; float f; } a; a.u = ((u32)h) << 16;
  return a.f;
}
__device__ __forceinline__ void g2l16(const u16* g, u16* l) {
  __builtin_amdgcn_global_load_lds((const __attribute__((address_space(1))) u32*)g,
                                   (__attribute__((address_space(3))) u32*)l, 16, 0, 0);
}

__global__ void k_f32_to_bf16(const float* __restrict__ in, u16* __restrict__ out, int n) {
  int i = (blockIdx.x * 256 + threadIdx.x) * 8;
  if (i >= n) return;
  float4 a = *(const float4*)(in + i);
  float4 b = *(const float4*)(in + i + 4);
  u16x8 v;
  v[0] = f2b(a.x); v[1] = f2b(a.y); v[2] = f2b(a.z); v[3] = f2b(a.w);
  v[4] = f2b(b.x); v[5] = f2b(b.y); v[6] = f2b(b.z); v[7] = f2b(b.w);
  *(u16x8*)(out + i) = v;
}

// out[c][r] = bf16(in[r][c]); in is R x C f32
__global__ void k_transpose_bf16(const float* __restrict__ in, u16* __restrict__ out,
                                 int R, int C) {
  __shared__ u16 tile[32][33];
  const int c0 = blockIdx.x * 32, r0 = blockIdx.y * 32;
  const int tx = threadIdx.x & 31, ty = threadIdx.x >> 5;
#pragma unroll
  for (int i = 0; i < 32; i += 8)
    tile[ty + i][tx] = f2b(in[(size_t)(r0 + ty + i) * C + c0 + tx]);
  __syncthreads();
#pragma unroll
  for (int i = 0; i < 32; i += 8)
    out[(size_t)(c0 + ty + i) * R + r0 + tx] = tile[tx][ty + i];
}

// ---------------------------------------------------------------------------
// QKV GEMM with fused RoPE + head-scatter epilogue (m97 128x128 structure).
// ROUND-11 VERSION (best measured: 136.8us) — the gemm_qkv line is CLOSED:
// r8 launch_bounds ignored; r9 waves_per_eu spilled acc (678MB); r10
// unroll-1 runtime-indexed acc (3GB, rule #20); r12 LDS-bounce cut VGPR
// 120->96 but occupancy didn't respond (+bank conflicts, slower). Fused
// (136.8) == split (116.6+18 scatter): epilogue cost is inherent work.
// q/k stored with interleaved d-permutation (d<64->2d, d>=64->2(d-64)+1);
// QK^T invariant since Q,K share it. V transposed to vtb[bh][d][t].
// ---------------------------------------------------------------------------
__global__ __launch_bounds__(256) void k_gemm_qkv(const u16* __restrict__ A,
                                                  const u16* __restrict__ B,
                                                  u16* __restrict__ qr,
                                                  u16* __restrict__ kr,
                                                  u16* __restrict__ vtb) {
  __shared__ __align__(16) u16 lA[128 * 64];
  __shared__ __align__(16) u16 lB[128 * 64];
  const int K = DMODEL;
  const int tid = threadIdx.x;
  const int wid = tid >> 6, lane = tid & 63;
  const int g = lane >> 4, q = lane & 15;
  const int wr = wid >> 1, wc = wid & 1;
  const int bn = blockIdx.x, bm = blockIdx.y;
  const int l8 = lane >> 3, l7 = lane & 7;
  const f32x4 fzero = {0.f, 0.f, 0.f, 0.f};
  f32x4 acc[4][4];
#pragma unroll
  for (int m = 0; m < 4; ++m)
#pragma unroll
    for (int n = 0; n < 4; ++n) acc[m][n] = fzero;

  const u16* Ab = A + (size_t)bm * 128 * K;
  const u16* Bb = B + (size_t)bn * 128 * K;

  for (int k0 = 0; k0 < K; k0 += 64) {
    __syncthreads();
#pragma unroll
    for (int i = 0; i < 4; ++i) {
      int chunk = wid * 4 + i;
      int row = chunk * 8 + l8;
      int scol = (l7 * 8) ^ ((row & 7) << 3);
      g2l16(Ab + (size_t)row * K + k0 + scol, lA + chunk * 512);
      g2l16(Bb + (size_t)row * K + k0 + scol, lB + chunk * 512);
    }
    __syncthreads();
#pragma unroll
    for (int kk = 0; kk < 2; ++kk) {
      bf16x8 af[4], bfr[4];
#pragma unroll
      for (int m = 0; m < 4; ++m) {
        int row = wr * 64 + m * 16 + q;
        int col = (kk * 32 + g * 8) ^ ((row & 7) << 3);
        af[m] = *(const bf16x8*)(lA + row * 64 + col);
      }
#pragma unroll
      for (int n = 0; n < 4; ++n) {
        int row = wc * 32 + (n & 1) * 16 + (n >> 1) * 64 + q;  // paired-col mapping
        int col = (kk * 32 + g * 8) ^ ((row & 7) << 3);
        bfr[n] = *(const bf16x8*)(lB + row * 64 + col);
      }
#pragma unroll
      for (int m = 0; m < 4; ++m)
#pragma unroll
        for (int n = 0; n < 4; ++n)
          acc[m][n] = __builtin_amdgcn_mfma_f32_16x16x32_bf16(af[m], bfr[n], acc[m][n], 0, 0, 0);
    }
  }
  __builtin_amdgcn_sched_barrier(0);

  // ---- fused epilogue (fully unrolled; on-the-fly sincos) ----
  const int h = bn & 15;
  const int which = bn >> 4;                 // 0=q, 1=k, 2=v
  const int b = bm >> 4;
  const int bh = b * 16 + h;
  const int tb0 = (bm & 15) * 128 + wr * 64; // + m*16 + g*4 + r -> token idx
  const float qscale = 0.08838834764831845f;

  if (which == 2) {
    // V: store transposed to vtb[bh][d][t]; 4 consecutive t packed per store.
    u16* vdst = vtb + (size_t)bh * HD * T_SEQ;
#pragma unroll
    for (int m = 0; m < 4; ++m)
#pragma unroll
      for (int n = 0; n < 4; ++n) {
        int c = wc * 32 + (n & 1) * 16 + (n >> 1) * 64 + q;
        int t0 = tb0 + m * 16 + g * 4;
        u16x4 pk;
#pragma unroll
        for (int r = 0; r < 4; ++r) pk[r] = f2b(acc[m][n][r]);
        *(u16x4*)(vdst + (size_t)c * T_SEQ + t0) = pk;
      }
  } else {
    u16* dst = (which ? kr : qr) + (size_t)bh * T_SEQ * HD;
    const float sc = which ? 1.0f : qscale;
#pragma unroll
    for (int n = 0; n < 2; ++n) {
      int dm = wc * 32 + n * 16 + q;        // d % 64
      // inv_freq = 10000^(-dm/64) = exp2(-dm * log2(10000)/64)
      float inv = exp2f(-(float)dm * 0.20762050592046521f);
#pragma unroll
      for (int m = 0; m < 4; ++m)
#pragma unroll
        for (int r = 0; r < 4; ++r) {
          int t = tb0 + m * 16 + g * 4 + r;
          float s, c;
          __sincosf((float)t * inv, &s, &c);
          float x0 = acc[m][n][r];          // d = dm (low half)
          float x1 = acc[m][n + 2][r];      // d = dm + 64 (high half)
          u32 pk = (u32)f2b((x0 * c - x1 * s) * sc) |
                   ((u32)f2b((x1 * c + x0 * s) * sc) << 16);
          *(u32*)(dst + (size_t)t * HD + dm * 2) = pk;  // interleaved d
        }
    }
  }
}

// m97-style 128x128 GEMM for the output projection (EPI=1: f32 out).
template <int EPI>
__global__ __launch_bounds__(256) void k_gemm_nt(const u16* __restrict__ A,
                                                 const u16* __restrict__ B,
                                                 void* __restrict__ Cv,
                                                 int M, int N, int K) {
  __shared__ __align__(16) u16 lA[128 * 64];
  __shared__ __align__(16) u16 lB[128 * 64];
  const int tid = threadIdx.x;
  const int wid = tid >> 6, lane = tid & 63;
  const int g = lane >> 4, q = lane & 15;
  const int wr = wid >> 1, wc = wid & 1;
  const int bn = blockIdx.x, bm = blockIdx.y;
  const int l8 = lane >> 3, l7 = lane & 7;
  const f32x4 fzero = {0.f, 0.f, 0.f, 0.f};
  f32x4 acc[4][4];
#pragma unroll
  for (int m = 0; m < 4; ++m)
#pragma unroll
    for (int n = 0; n < 4; ++n) acc[m][n] = fzero;

  const u16* Ab = A + (size_t)bm * 128 * K;
  const u16* Bb = B + (size_t)bn * 128 * K;

  for (int k0 = 0; k0 < K; k0 += 64) {
    __syncthreads();
#pragma unroll
    for (int i = 0; i < 4; ++i) {
      int chunk = wid * 4 + i;
      int row = chunk * 8 + l8;
      int scol = (l7 * 8) ^ ((row & 7) << 3);
      g2l16(Ab + (size_t)row * K + k0 + scol, lA + chunk * 512);
      g2l16(Bb + (size_t)row * K + k0 + scol, lB + chunk * 512);
    }
    __syncthreads();
#pragma unroll
    for (int kk = 0; kk < 2; ++kk) {
      bf16x8 af[4], bfr[4];
#pragma unroll
      for (int m = 0; m < 4; ++m) {
        int row = wr * 64 + m * 16 + q;
        int col = (kk * 32 + g * 8) ^ ((row & 7) << 3);
        af[m] = *(const bf16x8*)(lA + row * 64 + col);
      }
#pragma unroll
      for (int n = 0; n < 4; ++n) {
        int row = wc * 64 + n * 16 + q;
        int col = (kk * 32 + g * 8) ^ ((row & 7) << 3);
        bfr[n] = *(const bf16x8*)(lB + row * 64 + col);
      }
#pragma unroll
      for (int m = 0; m < 4; ++m)
#pragma unroll
        for (int n = 0; n < 4; ++n)
          acc[m][n] = __builtin_amdgcn_mfma_f32_16x16x32_bf16(af[m], bfr[n], acc[m][n], 0, 0, 0);
    }
  }
  const int rbase = bm * 128 + wr * 64;
  const int cbase = bn * 128 + wc * 64;
#pragma unroll
  for (int m = 0; m < 4; ++m)
#pragma unroll
    for (int n = 0; n < 4; ++n) {
      int col = cbase + n * 16 + q;
#pragma unroll
      for (int r = 0; r < 4; ++r) {
        int row = rbase + m * 16 + g * 4 + r;
        if (EPI == 0)
          ((u16*)Cv)[(size_t)row * N + col] = f2b(acc[m][n][r]);
        else
          ((float*)Cv)[(size_t)row * N + col] = acc[m][n][r];
      }
    }
}

// Flash attention, triangle-folded at QBLK=64: block does q-tile pair
// (31-y, y) = 33 k-tiles uniformly. Double-buffered K/V staging; diagonal-
// only causal mask; defer-max (T13). NEW (r13): XCD swizzle groups 4 bh
// per XCD (4MB K/V = one L2) — safe now that fold makes blocks uniform
// (r6's swizzle regression was the qt-pairing imbalance, not the swizzle);
// T5 setprio around MFMA clusters; rely on compiler lgkmcnt for the
// wave-private lP roundtrip (full drain over-serialized).
__global__ __launch_bounds__(256) void k_attn(const u16* __restrict__ qr,
                                              const u16* __restrict__ kr,
                                              const u16* __restrict__ vtb,
                                              u16* __restrict__ ao) {
  __shared__ __align__(16) u16 lK[2][64 * 128];
  __shared__ __align__(16) u16 lV[2][128 * 64];
  __shared__ __align__(16) u16 lP[4][16 * 72];
  // 512 blocks; (lin%8)*64+lin/8 is bijective; each XCD gets 4 bh x 16 y.
  const int lin = blockIdx.y * 32 + blockIdx.x;
  const int id2 = (lin & 7) * 64 + (lin >> 3);
  const int bh = id2 >> 4, b = bh >> 4, h = bh & 15;
  const int yy = id2 & 15;
  const int tid = threadIdx.x;
  const int wid = tid >> 6, lane = tid & 63;
  const int g = lane >> 4, q = lane & 15;
  const int l8 = lane >> 3, l7 = lane & 7;
  const u16* qb = qr + (size_t)bh * T_SEQ * HD;
  const u16* kbp = kr + (size_t)bh * T_SEQ * HD;
  const u16* vb = vtb + (size_t)bh * HD * T_SEQ;
  const f32x4 fzero = {0.f, 0.f, 0.f, 0.f};

  auto stageKV = [&](int kb, int bufI) {
#pragma unroll
    for (int i = 0; i < 4; ++i) {
      int chunk = wid * 4 + i;
      int row = chunk * 4 + g;
      int scol = (q * 8) ^ ((row & 7) << 3);
      g2l16(kbp + (size_t)(kb + row) * HD + scol, &lK[bufI][chunk * 512]);
    }
#pragma unroll
    for (int i = 0; i < 4; ++i) {
      int chunk = wid * 4 + i;
      int row = chunk * 8 + l8;
      int scol = (l7 * 8) ^ ((row & 7) << 3);
      g2l16(vb + (size_t)row * T_SEQ + kb + scol, &lV[bufI][chunk * 512]);
    }
  };

  for (int half = 0; half < 2; ++half) {
    const int qt = half ? yy : 31 - yy;
    const int qw0 = qt * 64 + wid * 16;

    bf16x8 qf[4];
#pragma unroll
    for (int ks = 0; ks < 4; ++ks)
      qf[ks] = *(const bf16x8*)(qb + (size_t)(qw0 + q) * HD + ks * 32 + g * 8);

    f32x4 o_acc[8];
#pragma unroll
    for (int n = 0; n < 8; ++n) o_acc[n] = fzero;
    float m_run = -1e30f, l_run = 0.f;

    const int ntiles = qt + 1;
    stageKV(0, 0);
    __syncthreads();                 // drains vmcnt -> buf0 ready
    for (int kt = 0; kt < ntiles; ++kt) {
      const int kb = kt * 64;
      const int cb = kt & 1;
      if (kt + 1 < ntiles) stageKV(kb + 64, cb ^ 1);   // prefetch next tile
      const u16* lKc = lK[cb];
      const u16* lVc = lV[cb];
      {
        f32x4 st[4];
#pragma unroll
        for (int m = 0; m < 4; ++m) st[m] = fzero;
        __builtin_amdgcn_s_setprio(1);
#pragma unroll
        for (int ks = 0; ks < 4; ++ks) {
#pragma unroll
          for (int m = 0; m < 4; ++m) {
            int row = m * 16 + q;
            int col = (ks * 32 + g * 8) ^ ((row & 7) << 3);
            bf16x8 kf = *(const bf16x8*)(lKc + row * 128 + col);
            st[m] = __builtin_amdgcn_mfma_f32_16x16x32_bf16(kf, qf[ks], st[m], 0, 0, 0);
          }
        }
        __builtin_amdgcn_s_setprio(0);
        const int qrow = qw0 + q;
        float p[4][4];
        float pmax = -1e30f;
        if (kt == ntiles - 1) {
          // diagonal tile: causal mask
#pragma unroll
          for (int m = 0; m < 4; ++m)
#pragma unroll
            for (int r = 0; r < 4; ++r) {
              int kcol = kb + m * 16 + g * 4 + r;
              float s = (kcol <= qrow) ? st[m][r] : -1e30f;
              p[m][r] = s;
              pmax = fmaxf(pmax, s);
            }
        } else {
#pragma unroll
          for (int m = 0; m < 4; ++m)
#pragma unroll
            for (int r = 0; r < 4; ++r) {
              p[m][r] = st[m][r];
              pmax = fmaxf(pmax, st[m][r]);
            }
        }
        pmax = fmaxf(pmax, __shfl_xor(pmax, 16));
        pmax = fmaxf(pmax, __shfl_xor(pmax, 32));
        // defer-max (T13, THR=0): skip rescale when no lane's max grew.
        const bool noresc = __all(pmax <= m_run);
        const float m_new = noresc ? m_run : fmaxf(m_run, pmax);
        float ls = 0.f;
#pragma unroll
        for (int m = 0; m < 4; ++m)
#pragma unroll
          for (int r = 0; r < 4; ++r) {
            float e = __expf(p[m][r] - m_new);
            p[m][r] = e;
            ls += e;
          }
        ls += __shfl_xor(ls, 16);
        ls += __shfl_xor(ls, 32);
#pragma unroll
        for (int m = 0; m < 4; ++m) {
#pragma unroll
          for (int rp = 0; rp < 2; ++rp) {
            u32 pk = (u32)f2b(p[m][rp * 2]) | ((u32)f2b(p[m][rp * 2 + 1]) << 16);
            *(u32*)(&lP[wid][q * 72 + m * 16 + g * 4 + rp * 2]) = pk;
          }
        }
        if (noresc) {
          l_run += ls;
        } else {
          float corr = __expf(m_run - m_new);
          l_run = l_run * corr + ls;
          m_run = m_new;
          float corr4[4];
#pragma unroll
          for (int r = 0; r < 4; ++r) corr4[r] = __shfl(corr, g * 4 + r);
#pragma unroll
          for (int n = 0; n < 8; ++n) {
#pragma unroll
            for (int r = 0; r < 4; ++r) o_acc[n][r] *= corr4[r];
          }
        }
        __builtin_amdgcn_s_setprio(1);
#pragma unroll
        for (int ks = 0; ks < 2; ++ks) {
          bf16x8 pf = *(const bf16x8*)(&lP[wid][q * 72 + ks * 32 + g * 8]);
#pragma unroll
          for (int n = 0; n < 8; ++n) {
            int row = n * 16 + q;
            int col = (ks * 32 + g * 8) ^ ((row & 7) << 3);
            bf16x8 vf = *(const bf16x8*)(lVc + row * 64 + col);
            o_acc[n] = __builtin_amdgcn_mfma_f32_16x16x32_bf16(pf, vf, o_acc[n], 0, 0, 0);
          }
        }
        __builtin_amdgcn_s_setprio(0);
      }
      __syncthreads();               // drains vmcnt: prefetched buf ready; LDS reads done
    }
    float linv[4];
#pragma unroll
    for (int r = 0; r < 4; ++r) {
      float lv = __shfl(l_run, g * 4 + r);
      linv[r] = 1.0f / lv;
    }
#pragma unroll
    for (int n = 0; n < 8; ++n)
#pragma unroll
      for (int r = 0; r < 4; ++r) {
        int trow = qw0 + g * 4 + r;
        ao[(size_t)(b * T_SEQ + trow) * DMODEL + h * HD + n * 16 + q] = f2b(o_acc[n][r] * linv[r]);
      }
  }
}

extern "C" void kernel_launch(void* const* d_in, const int* in_sizes, int n_in,
                              void* d_out, int out_size, void* d_ws, size_t ws_size,
                              hipStream_t stream) {
  const float* x = (const float*)d_in[0];
  const float* w_qkv = (const float*)d_in[1];
  const float* w_out = (const float*)d_in[2];
  char* ws = (char*)d_ws;
  size_t off = 0;
  u16* xb = (u16*)(ws + off);    off += (size_t)MROWS * DMODEL * 2;   // also reused as ao
  u16* wqkvT = (u16*)(ws + off); off += (size_t)NQKV * DMODEL * 2;
  u16* woutT = (u16*)(ws + off); off += (size_t)DMODEL * DMODEL * 2;
  u16* qr = (u16*)(ws + off);    off += (size_t)32 * T_SEQ * HD * 2;
  u16* kr = (u16*)(ws + off);    off += (size_t)32 * T_SEQ * HD * 2;
  u16* vtb = (u16*)(ws + off);   off += (size_t)32 * T_SEQ * HD * 2;
  u16* ao = xb;

  k_f32_to_bf16<<<dim3(MROWS * DMODEL / (256 * 8)), 256, 0, stream>>>(x, xb, MROWS * DMODEL);
  k_transpose_bf16<<<dim3(NQKV / 32, DMODEL / 32), 256, 0, stream>>>(w_qkv, wqkvT, DMODEL, NQKV);
  k_transpose_bf16<<<dim3(DMODEL / 32, DMODEL / 32), 256, 0, stream>>>(w_out, woutT, DMODEL, DMODEL);
  k_gemm_qkv<<<dim3(48, 32), 256, 0, stream>>>(xb, wqkvT, qr, kr, vtb);
  k_attn<<<dim3(32, 16), 256, 0, stream>>>(qr, kr, vtb, ao);
  k_gemm_nt<1><<<dim3(DMODEL / 128, MROWS / 128), 256, 0, stream>>>(ao, woutT, d_out, MROWS, DMODEL, DMODEL);
}